// Round 1
// baseline (540.768 us; speedup 1.0000x reference)
//
#include <hip/hip_runtime.h>
#include <cstdint>
#include <cstddef>

#define DIM 256
#define NH 4
#define W 8
#define EB 16
#define SCALE 0.125f

typedef __bf16 bf16x8 __attribute__((ext_vector_type(8)));
typedef float f32x4 __attribute__((ext_vector_type(4)));
typedef unsigned short u16x4 __attribute__((ext_vector_type(4)));

__device__ __forceinline__ f32x4 ld4(const float* p) { return *(const f32x4*)p; }
__device__ __forceinline__ f32x4 ld4_nt(const float* p) {
  return __builtin_nontemporal_load((const f32x4*)p);
}
__device__ __forceinline__ float b2f(unsigned short u) {
  unsigned int x = ((unsigned int)u) << 16;
  return __builtin_bit_cast(float, x);
}
__device__ __forceinline__ unsigned short f2b(float f) {
  __bf16 b = (__bf16)f;
  return __builtin_bit_cast(unsigned short, b);
}

// ---------------------------------------------------------------------------
// Precompute 1: Astack = [SCALE * Wq_n^T Wk_n]_n stacked to (256 k x 1024 col),
// stored bf16 in MFMA-B-fragment swizzled layout: [kt 8][nt 64][lane 64][j 8]
// where k = kt*32 + (lane>>4)*8 + j, col = nt*16 + (lane&15).
// ---------------------------------------------------------------------------
__global__ void precomp_a(const float* __restrict__ Wq, const float* __restrict__ Wk,
                          unsigned short* __restrict__ Asw) {
  int blk = blockIdx.x;              // kt*64 + nt   (512 blocks)
  int kt = blk >> 6, nt = blk & 63;
  for (int x = threadIdx.x; x < 512; x += 256) {
    int lane = x & 63, j = x >> 6;
    int k = kt * 32 + ((lane >> 4) * 8) + j;
    int col = nt * 16 + (lane & 15);
    int n = col >> 8, b = col & 255;
    float s = 0.f;
#pragma unroll 8
    for (int d = 0; d < 64; ++d)
      s += Wq[(n * 64 + d) * 256 + k] * Wk[(n * 64 + d) * 256 + b];
    Asw[(size_t)blk * 512 + (size_t)lane * 8 + j] = f2b(s * SCALE);
  }
}

// ---------------------------------------------------------------------------
// Precompute 2 (general-bias terms; bq/bk/bv are zero in this problem but
// handled anyway): u_stack, wvo, v->Bvsw (swizzled, 4 used cols), s[4], c0.
// ---------------------------------------------------------------------------
__global__ void precomp_b(const float* __restrict__ Wq, const float* __restrict__ Wk,
                          const float* __restrict__ Wv, const float* __restrict__ bq,
                          const float* __restrict__ bk, const float* __restrict__ bv,
                          const float* __restrict__ Wo, const float* __restrict__ bo,
                          unsigned short* __restrict__ Bvsw, float* __restrict__ u_stack,
                          float* __restrict__ wvo, float* __restrict__ consts) {
  __shared__ float v_s[1024];
  int t = threadIdx.x;
  for (int col = t; col < 1024; col += 256) {
    int n = col >> 8, b = col & 255;
    float su = 0.f, sw = 0.f, sv = 0.f;
#pragma unroll 8
    for (int d = 0; d < 64; ++d) {
      float wkv = Wk[(n * 64 + d) * 256 + b];
      su += bq[n * 64 + d] * wkv;
      sw += Wv[(n * 64 + d) * 256 + b] * Wo[n * 64 + d];
      sv += Wq[(n * 64 + d) * 256 + b] * bk[n * 64 + d];
    }
    u_stack[col] = su * SCALE;
    wvo[col] = sw;
    v_s[col] = sv * SCALE;
  }
  __syncthreads();
  for (int x = t; x < 8 * 64 * 8; x += 256) {   // [kt][lane][j]
    int j = x & 7, lane = (x >> 3) & 63, kt = x >> 9;
    int colc = lane & 15;
    int k = kt * 32 + ((lane >> 4) * 8) + j;
    unsigned short val = 0;
    if (colc < 4) val = f2b(v_s[colc * 256 + k]);
    Bvsw[x] = val;
  }
  if (t < 4) {
    float s = 0.f;
    for (int d = 0; d < 64; ++d) s += bq[t * 64 + d] * bk[t * 64 + d];
    consts[t] = s * SCALE;
  }
  if (t == 4) {
    float s = bo[0];
    for (int d = 0; d < 256; ++d) s += bv[d] * Wo[d];
    consts[4] = s;
  }
}

// ---------------------------------------------------------------------------
// Fused main kernel: per block of 16 edges:
//  phase 1: t = bf16(h) @ Astack via MFMA (wave n owns head n)  -> t_lds (bf16)
//  phase 2: stream evol through LDS in 2-edge chunks; per-head octet dots,
//           softmax over W, head partial logit -> part_lds
//  phase 3: var means, combine heads, sigmoid -> out
// ---------------------------------------------------------------------------
__global__ __launch_bounds__(256, 2) void fused_main(
    const float* __restrict__ h_i, const float* __restrict__ evol,
    const float* __restrict__ evt, const float* __restrict__ var_i,
    const float* __restrict__ var_j, const float* __restrict__ cur_t,
    const float* __restrict__ tdp, const float* __restrict__ Wu,
    const float* __restrict__ bup, const unsigned short* __restrict__ Asw,
    const unsigned short* __restrict__ Bvsw, const float* __restrict__ u_stack,
    const float* __restrict__ wvo, const float* __restrict__ consts,
    float* __restrict__ out) {

  __shared__ unsigned short t_lds[EB][1024];   // 32 KB  (bf16 bits)
  __shared__ float ev_lds[2][W][DIM];          // 16 KB  (2-edge chunk)
  __shared__ float part_lds[EB][NH];           // 256 B
  __shared__ float r_lds[EB][NH];              // 256 B

  const int tid = threadIdx.x;
  const int wid = tid >> 6;        // wave index == head index
  const int lane = tid & 63;
  const int e0 = blockIdx.x * EB;

  // ---------------- phase 1: GEMM t = h @ Astack ----------------
  const int row = lane & 15;       // edge within block (M)
  const int kg = lane >> 4;        // k-group
  f32x4 zero4 = {0.f, 0.f, 0.f, 0.f};
  f32x4 acc[16];
#pragma unroll
  for (int i = 0; i < 16; ++i) acc[i] = zero4;
  f32x4 accr = zero4;

  const float* hrow = h_i + (size_t)(e0 + row) * DIM + kg * 8;
  const bf16x8* asw_b = (const bf16x8*)Asw;
  const bf16x8* bv_b = (const bf16x8*)Bvsw;

#pragma unroll
  for (int ks = 0; ks < 8; ++ks) {
    f32x4 a0 = ld4(hrow + ks * 32);
    f32x4 a1 = ld4(hrow + ks * 32 + 4);
    bf16x8 af;
    af[0] = (__bf16)a0[0]; af[1] = (__bf16)a0[1]; af[2] = (__bf16)a0[2]; af[3] = (__bf16)a0[3];
    af[4] = (__bf16)a1[0]; af[5] = (__bf16)a1[1]; af[6] = (__bf16)a1[2]; af[7] = (__bf16)a1[3];
    const bf16x8* bb = asw_b + (size_t)(ks * 64 + wid * 16) * 64 + lane;
#pragma unroll
    for (int nt = 0; nt < 16; ++nt) {
      bf16x8 bf = bb[(size_t)nt * 64];
      acc[nt] = __builtin_amdgcn_mfma_f32_16x16x32_bf16(af, bf, acc[nt], 0, 0, 0);
    }
    if (wid == 0) {  // extra tile: r[edge][n] = h . v_n  (bias term; zero here)
      bf16x8 bvf = bv_b[ks * 64 + lane];
      accr = __builtin_amdgcn_mfma_f32_16x16x32_bf16(af, bvf, accr, 0, 0, 0);
    }
  }
  // D layout: edge = kg*4 + r, dim = wid*256 + nt*16 + row   [m89-verified]
#pragma unroll
  for (int nt = 0; nt < 16; ++nt) {
    int dim = wid * 256 + nt * 16 + row;
    float uv = u_stack[dim];
#pragma unroll
    for (int r = 0; r < 4; ++r)
      t_lds[kg * 4 + r][dim] = f2b(acc[nt][r] + uv);
  }
  if (wid == 0 && row < 4) {
    float sv = consts[row];
#pragma unroll
    for (int r = 0; r < 4; ++r) r_lds[kg * 4 + r][row] = accr[r] + sv;
  }

  // ---------------- phase 2: epilogue ----------------
  const int c = lane & 7;          // dim-chunk index (dims c*4 + 32k + j)
  const int oct = lane >> 3;       // window index wv
  f32x4 wvoR[8], wuR[8];
#pragma unroll
  for (int k = 0; k < 8; ++k) {
    wvoR[k] = ld4(wvo + wid * 256 + k * 32 + c * 4);
    wuR[k] = ld4(Wu + k * 32 + c * 4);
  }
  const float tdec = fabsf(tdp[0]);
  const float buv = bup[0];

  for (int ch = 0; ch < 8; ++ch) {
    __syncthreads();  // t_lds ready (ch=0) / previous chunk consumed
    {  // stage 2 edges (16 KB) into LDS, contiguous, non-temporal
      const f32x4* src = (const f32x4*)(evol + (size_t)(e0 + ch * 2) * (W * DIM));
      f32x4* dst = (f32x4*)&ev_lds[0][0][0];
#pragma unroll
      for (int i = 0; i < 4; ++i)
        dst[i * 256 + tid] = ld4_nt((const float*)(src + i * 256 + tid));
    }
    __syncthreads();  // staging complete
#pragma unroll
    for (int e = 0; e < 2; ++e) {
      const int m = ch * 2 + e;
      const float* evb = &ev_lds[e][oct][c * 4];
      const unsigned short* tb = &t_lds[m][wid * 256 + c * 4];
      float dt = 0.f, dg = 0.f, du = 0.f;
#pragma unroll
      for (int k = 0; k < 8; ++k) {
        f32x4 ev = ld4(evb + k * 32);
        u16x4 tu = *(const u16x4*)(tb + k * 32);
        dt += ev[0] * b2f(tu[0]) + ev[1] * b2f(tu[1]) + ev[2] * b2f(tu[2]) + ev[3] * b2f(tu[3]);
        dg += ev[0] * wvoR[k][0] + ev[1] * wvoR[k][1] + ev[2] * wvoR[k][2] + ev[3] * wvoR[k][3];
        du += ev[0] * wuR[k][0] + ev[1] * wuR[k][1] + ev[2] * wuR[k][2] + ev[3] * wuR[k][3];
      }
#pragma unroll
      for (int s = 1; s < 8; s <<= 1) {  // reduce over dim-chunks within octet
        dt += __shfl_xor(dt, s);
        dg += __shfl_xor(dg, s);
        du += __shfl_xor(du, s);
      }
      float tev = evt[(size_t)(e0 + m) * W + oct];
      float tbias = -tdec * fmaxf(cur_t[e0 + m] - tev, 0.f);
      float unc = 1.f / (1.f + __expf(-(du + buv)));
      float logit = (dt + r_lds[m][wid] + tbias) * unc;
      float mx = logit;
#pragma unroll
      for (int s = 8; s < 64; s <<= 1) mx = fmaxf(mx, __shfl_xor(mx, s));
      float p = __expf(logit - mx);
      float pg = p * dg, ps = p;
#pragma unroll
      for (int s = 8; s < 64; s <<= 1) { ps += __shfl_xor(ps, s); pg += __shfl_xor(pg, s); }
      if (lane == 0) part_lds[m][wid] = pg / ps;  // head's pooled . Wo_n
    }
  }
  __syncthreads();

  // ---------------- phase 3: conf + output ----------------
  const float c0 = consts[4];
#pragma unroll
  for (int e = 0; e < 4; ++e) {
    const int m = wid * 4 + e;
    f32x4 vi = ld4_nt(var_i + (size_t)(e0 + m) * DIM + lane * 4);
    f32x4 vj = ld4_nt(var_j + (size_t)(e0 + m) * DIM + lane * 4);
    float si = vi[0] + vi[1] + vi[2] + vi[3];
    float sj = vj[0] + vj[1] + vj[2] + vj[3];
#pragma unroll
    for (int s = 1; s < 64; s <<= 1) { si += __shfl_xor(si, s); sj += __shfl_xor(sj, s); }
    if (lane == 0) {
      float logit = part_lds[m][0] + part_lds[m][1] + part_lds[m][2] + part_lds[m][3] + c0;
      float ci = 1.f / (1.f + fmaxf(sqrtf(si * (1.f / 256.f)), 1e-6f));
      float cj = 1.f / (1.f + fmaxf(sqrtf(sj * (1.f / 256.f)), 1e-6f));
      out[e0 + m] = 1.f / (1.f + __expf(-logit * ci * cj));
    }
  }
}

extern "C" void kernel_launch(void* const* d_in, const int* in_sizes, int n_in,
                              void* d_out, int out_size, void* d_ws, size_t ws_size,
                              hipStream_t stream) {
  const float* h_i = (const float*)d_in[0];
  // d_in[1] (h_j) is unused by the reference
  const float* evol = (const float*)d_in[2];
  const float* evt = (const float*)d_in[3];
  const float* var_i = (const float*)d_in[4];
  const float* var_j = (const float*)d_in[5];
  const float* ct = (const float*)d_in[6];
  const float* Wq = (const float*)d_in[7];
  const float* bq = (const float*)d_in[8];
  const float* Wk = (const float*)d_in[9];
  const float* bk = (const float*)d_in[10];
  const float* Wv = (const float*)d_in[11];
  const float* bv = (const float*)d_in[12];
  const float* td = (const float*)d_in[13];
  const float* Wu = (const float*)d_in[14];
  const float* bu = (const float*)d_in[15];
  const float* Wo = (const float*)d_in[16];
  const float* bo = (const float*)d_in[17];
  float* out = (float*)d_out;

  char* ws = (char*)d_ws;
  unsigned short* Asw = (unsigned short*)ws;               // 512 KB
  unsigned short* Bvsw = (unsigned short*)(ws + 524288);   // 8 KB
  float* u_stack = (float*)(ws + 532480);                  // 4 KB
  float* wvo = (float*)(ws + 536576);                      // 4 KB
  float* consts = (float*)(ws + 540672);                   // 32 B

  const int E = in_sizes[6];  // 100000; EB=16 divides exactly (6250 blocks)

  precomp_a<<<512, 256, 0, stream>>>(Wq, Wk, Asw);
  precomp_b<<<1, 256, 0, stream>>>(Wq, Wk, Wv, bq, bk, bv, Wo, bo, Bvsw, u_stack, wvo, consts);
  fused_main<<<E / EB, 256, 0, stream>>>(h_i, evol, evt, var_i, var_j, ct, td, Wu, bu,
                                         Asw, Bvsw, u_stack, wvo, consts, out);
}